// Round 6
// baseline (10029.107 us; speedup 1.0000x reference)
//
#include <hip/hip_runtime.h>
#include <stdint.h>

typedef __attribute__((ext_vector_type(8))) short short8;
typedef __attribute__((ext_vector_type(4))) float fl4;
typedef __attribute__((ext_vector_type(8))) unsigned short us8;

#define SAT_HI 1.0e6f
#define ZSLOT 262144u            // elements per z slot (64*4096 bf16)

__device__ __forceinline__ unsigned short f2bf(float f) {
  unsigned u = __float_as_uint(f);
  u += 0x7fffu + ((u >> 16) & 1u);   // RNE
  return (unsigned short)(u >> 16);
}
__device__ __forceinline__ float clipf(float x) {
  return fminf(fmaxf(x, 0.0f), SAT_HI);
}

__device__ __forceinline__ void gload16(const void* g, void* l) {
  __builtin_amdgcn_global_load_lds(
      (const __attribute__((address_space(1))) void*)g,
      (__attribute__((address_space(3))) void*)l, 16, 0, 0);
}

// ---- pack W (f32 [N][N]) into bf16 MFMA B-fragments ----
// u = [ct:6][w:4][nc:2][ki:3][lane:6]; block-col ct owns n in [64ct,64ct+64),
// wave w owns k in [256w,256w+256). lane: n = 64ct+16nc+(lane&15),
// k = 256w+32ki+8*(lane>>4). B[k][n] = W[n][k]  (y = z @ W^T)
__global__ __launch_bounds__(256) void prep_kernel(const float* __restrict__ W,
                                                   unsigned short* __restrict__ wfrag) {
  unsigned u = blockIdx.x * 256u + threadIdx.x;        // < 2097152
  unsigned lane = u & 63u, lo = lane & 15u, hi = lane >> 4;
  unsigned ki = (u >> 6) & 7u;
  unsigned nc = (u >> 9) & 3u;
  unsigned w = (u >> 11) & 15u;
  unsigned ct = u >> 15;               // 0..63
  unsigned n = ct * 64u + nc * 16u + lo;
  unsigned k = w * 256u + ki * 32u + hi * 8u;
  const float* src = W + (size_t)n * 4096u + k;
  fl4 s0 = *(const fl4*)(src);
  fl4 s1 = *(const fl4*)(src + 4);
  us8 o;
  o[0] = f2bf(s0[0]); o[1] = f2bf(s0[1]); o[2] = f2bf(s0[2]); o[3] = f2bf(s0[3]);
  o[4] = f2bf(s1[0]); o[5] = f2bf(s1[1]); o[6] = f2bf(s1[2]); o[7] = f2bf(s1[3]);
  *(us8*)(wfrag + (size_t)u * 8u) = o;
}

__global__ __launch_bounds__(1024, 4) void persist_kernel(
    const float* __restrict__ xin,     // [C][B][T]
    const float* __restrict__ state0,  // [B][N]
    const float* __restrict__ mask,    // [N]
    const float* __restrict__ enc,     // [C][N]
    const float* __restrict__ bias,    // [N]
    const float* __restrict__ decw,    // [C][N]
    const unsigned short* __restrict__ wfrag,
    unsigned short* __restrict__ zbuf, // [3][B][N] bf16
    float* __restrict__ dsc8,          // [8][C][B][T] f32, atomically accumulated
    int* __restrict__ cnt) {
  // 16 waves x 8 KB stage buffers = 128 KB; after MFMA each wave's f32 partial
  // block [16][68] (4352 B) is aliased into its OWN stage buffer.
  __shared__ __align__(16) unsigned char sm[131072];

  const int tid = threadIdx.x;
  const int wave = tid >> 6;           // 0..15, owns K-sixteenth
  const int lane = tid & 63;
  const int lo = lane & 15, hi = lane >> 4;
  const int g = blockIdx.x;
  const int rt = g & 3, ct = g >> 2;   // row-tile 0..3, col-tile 0..63
  const int grp = g & 7;               // barrier group (same-XCD blocks)
  float* dscg = dsc8 + (size_t)(ct & 7) * 131072u;  // decode copy: 8-way fan-in

  // persistent W fragments: 32 x short8 = 128 VGPRs  (wf[nc*8+ki])
  short8 wf[32];
  {
    const short8* wp = (const short8*)wfrag + ((size_t)(ct * 16 + wave) * 32u) * 64u + lane;
#pragma unroll
    for (int f = 0; f < 32; ++f) wf[f] = wp[(size_t)f * 64u];
  }

  // phase-B role: one output element per thread: local row r = wave, col c = lane
  const int r = wave, c = lane;
  const int b = rt * 16 + r;           // global batch row
  const int n = ct * 64 + c;           // global neuron col
  const float mk = mask[n];
  const float bi = bias[n];
  const float e0 = enc[n], e1 = enc[4096 + n], e2 = enc[8192 + n], e3 = enc[12288 + n];
  const float w0 = decw[n], w1 = decw[4096 + n], w2 = decw[8192 + n], w3 = decw[12288 + n];
  const float* xp = xin + b * 512;     // x[ch][b][t] = xp[ch*32768 + t]
  const int kwb = wave * 512;          // byte offset of wave's K-slice in a z row

  char* mybuf = (char*)sm + wave * 8192;
  float* pown = (float*)mybuf;         // aliased partial region [16][68] f32
  int* gcnt = cnt;
  int* xcnt = cnt + 32 + grp * 32;

  int ep = 0;

  // prologue: z_0 -> slot 0 (write-through)
  {
    float st = state0[(size_t)b * 4096u + n];
    float x0 = xp[0], x1 = xp[32768], x2 = xp[65536], x3 = xp[98304];
    float z = st + mk * (x0 * e0 + x1 * e1 + x2 * e2 + x3 * e3);
    __hip_atomic_store(zbuf + (size_t)b * 4096u + n, f2bf(z),
                       __ATOMIC_RELAXED, __HIP_MEMORY_SCOPE_SYSTEM);
  }
  // full barrier (arrive+wait, no overlap work yet)
  {
    ++ep;
    __syncthreads();
    if (tid == 0) {
      int old = __hip_atomic_fetch_add(xcnt, 1, __ATOMIC_RELAXED, __HIP_MEMORY_SCOPE_AGENT);
      if (old == ep * 32 - 1)
        __hip_atomic_fetch_add(gcnt, 1, __ATOMIC_RELAXED, __HIP_MEMORY_SCOPE_AGENT);
      while (__hip_atomic_load(gcnt, __ATOMIC_RELAXED, __HIP_MEMORY_SCOPE_AGENT) < ep * 8)
        __builtin_amdgcn_s_sleep(1);
      (void)__hip_atomic_load(gcnt, __ATOMIC_ACQUIRE, __HIP_MEMORY_SCOPE_AGENT);
    }
    __syncthreads();
  }

  float pdv = 0.f;                     // deferred decode value (lanes 0,16,32,48)
  int slot = 0;
  for (int t = 0; t < 512; ++t) {
    // ---- phase A1: issue staging FIRST (critical path): 16 rows x 512 B ----
    const char* zsrc = (const char*)(zbuf + (size_t)slot * ZSLOT) + (size_t)(rt * 16) * 8192 + kwb;
#pragma unroll
    for (int i = 0; i < 8; ++i) {
      const int row = 2 * i + (lane >> 5);      // local row 0..15
      gload16(zsrc + (size_t)row * 8192 + ((((unsigned)lane & 31u) ^ ((unsigned)row & 7u)) << 4),
              mybuf + i * 1024);
    }
    // ---- A2: previous step's decode atomics (drain under staging) ----
    if (t > 0 && (lane & 15) == 0)
      atomicAdd(dscg + (lane >> 4) * 32768 + b * 512 + (t - 1), pdv);
    // ---- A3: next-step x prefetch ----
    float xv0 = 0.f, xv1 = 0.f, xv2 = 0.f, xv3 = 0.f;
    if (t < 511) {
      xv0 = xp[t + 1]; xv1 = xp[32768 + t + 1];
      xv2 = xp[65536 + t + 1]; xv3 = xp[98304 + t + 1];
    }
    // ---- A4: wait staging, MFMA over own K-slice: [16 rows][64 cols] ----
    asm volatile("s_waitcnt vmcnt(0)" ::: "memory");
    __builtin_amdgcn_sched_barrier(0);
    fl4 acc0 = {0.f,0.f,0.f,0.f}, acc1 = acc0, acc2 = acc0, acc3 = acc0;
#pragma unroll
    for (int ki = 0; ki < 8; ++ki) {
      short8 a = *(const short8*)(mybuf + lo * 512 +
                                  ((ki * 64 + hi * 16) ^ ((lo & 7) << 4)));
      acc0 = __builtin_amdgcn_mfma_f32_16x16x32_bf16(a, wf[ki], acc0, 0, 0, 0);
      acc1 = __builtin_amdgcn_mfma_f32_16x16x32_bf16(a, wf[8 + ki], acc1, 0, 0, 0);
      acc2 = __builtin_amdgcn_mfma_f32_16x16x32_bf16(a, wf[16 + ki], acc2, 0, 0, 0);
      acc3 = __builtin_amdgcn_mfma_f32_16x16x32_bf16(a, wf[24 + ki], acc3, 0, 0, 0);
    }
    // ---- A5: stash per-wave partials (aliased into own stage buffer) ----
#pragma unroll
    for (int rr = 0; rr < 4; ++rr) {
      pown[(hi * 4 + rr) * 68 + lo] = acc0[rr];
      pown[(hi * 4 + rr) * 68 + 16 + lo] = acc1[rr];
      pown[(hi * 4 + rr) * 68 + 32 + lo] = acc2[rr];
      pown[(hi * 4 + rr) * 68 + 48 + lo] = acc3[rr];
    }
    __syncthreads();

    // ---- phase B: reduce over 16 waves + state update ----
    float y = 0.f;
#pragma unroll
    for (int w = 0; w < 16; ++w)
      y += ((const float*)sm)[w * 2048 + r * 68 + c];
    float sn = mk * (bi + clipf(y));

    // next z FIRST (critical path for step t+1), write-through
    if (t < 511) {
      int ns = slot + 1; if (ns == 3) ns = 0;
      float z = sn + mk * (xv0 * e0 + xv1 * e1 + xv2 * e2 + xv3 * e3);
      __hip_atomic_store(zbuf + (size_t)ns * ZSLOT + (size_t)b * 4096u + n, f2bf(z),
                         __ATOMIC_RELAXED, __HIP_MEMORY_SCOPE_SYSTEM);
      slot = ns;
    }

    // ---- barrier ARRIVE (z-store drained by syncthreads' vmcnt drain) ----
    int e = 0;
    if (t < 511) {
      e = ++ep;
      __syncthreads();
      if (tid == 0) {
        int old = __hip_atomic_fetch_add(xcnt, 1, __ATOMIC_RELAXED, __HIP_MEMORY_SCOPE_AGENT);
        if (old == e * 32 - 1)
          __hip_atomic_fetch_add(gcnt, 1, __ATOMIC_RELAXED, __HIP_MEMORY_SCOPE_AGENT);
      }
    }

    // ---- decode reduce (overlaps with other blocks' arrivals) ----
    // after xor16+xor32, lane l holds S_{l&15}(ch) for all 4 ch
    float d0 = sn * w0, d1 = sn * w1, d2 = sn * w2, d3 = sn * w3;
    d0 += __shfl_xor(d0, 16); d0 += __shfl_xor(d0, 32);
    d1 += __shfl_xor(d1, 16); d1 += __shfl_xor(d1, 32);
    d2 += __shfl_xor(d2, 16); d2 += __shfl_xor(d2, 32);
    d3 += __shfl_xor(d3, 16); d3 += __shfl_xor(d3, 32);
    const int q = lane >> 4;             // quarter picks its channel
    float v = (q < 2) ? (q == 0 ? d0 : d1) : (q == 2 ? d2 : d3);
    v += __shfl_xor(v, 1); v += __shfl_xor(v, 2);
    v += __shfl_xor(v, 4); v += __shfl_xor(v, 8);
    pdv = v;                             // lanes 0,16,32,48 hold channel sums

    // ---- barrier WAIT ----
    if (t < 511) {
      if (tid == 0) {
        while (__hip_atomic_load(gcnt, __ATOMIC_RELAXED, __HIP_MEMORY_SCOPE_AGENT) < e * 8)
          __builtin_amdgcn_s_sleep(1);
        (void)__hip_atomic_load(gcnt, __ATOMIC_ACQUIRE, __HIP_MEMORY_SCOPE_AGENT);
      }
      __syncthreads();
    }
  }
  // flush last step's decode
  if ((lane & 15) == 0)
    atomicAdd(dscg + (lane >> 4) * 32768 + b * 512 + 511, pdv);
}

__global__ __launch_bounds__(256) void final_kernel(const float* __restrict__ dsc8,
                                                    const float* __restrict__ decb,
                                                    float* __restrict__ out) {
  const unsigned u = blockIdx.x * 256u + threadIdx.x;  // < 131072, [C][B][T]
  const unsigned c = u >> 15;
  float s = decb[c];
#pragma unroll
  for (int g = 0; g < 8; ++g) s += dsc8[(size_t)g * 131072u + u];
  out[u] = clipf(s);
}

extern "C" void kernel_launch(void* const* d_in, const int* in_sizes, int n_in,
                              void* d_out, int out_size, void* d_ws, size_t ws_size,
                              hipStream_t stream) {
  const float* xin  = (const float*)d_in[0];
  const float* st   = (const float*)d_in[1];
  const float* mask = (const float*)d_in[2];
  const float* W    = (const float*)d_in[3];
  const float* enc  = (const float*)d_in[4];
  const float* bias = (const float*)d_in[5];
  const float* decw = (const float*)d_in[6];
  const float* decb = (const float*)d_in[7];
  char* ws = (char*)d_ws;

  const size_t WFRAG_B = 33554432ull;             // 32 MB
  const size_t Z_B     = 3ull * 524288ull;        // 1.5 MB (3-slot ring)
  const size_t DSC_B   = 4194304ull;              // 8 copies x 512 KB
  unsigned short* wfrag = (unsigned short*)(ws);
  unsigned short* zbuf  = (unsigned short*)(ws + WFRAG_B);
  float* dsc8 = (float*)(ws + WFRAG_B + Z_B);
  int* cnt    = (int*)(ws + WFRAG_B + Z_B + DSC_B);

  hipMemsetAsync(cnt, 0, 4096, stream);
  hipMemsetAsync(dsc8, 0, DSC_B, stream);
  prep_kernel<<<8192, 256, 0, stream>>>(W, wfrag);
  persist_kernel<<<256, 1024, 0, stream>>>(xin, st, mask, enc, bias, decw,
                                           wfrag, zbuf, dsc8, cnt);
  final_kernel<<<512, 256, 0, stream>>>(dsc8, decb, (float*)d_out);
}

// Round 7
// 5603.426 us; speedup vs baseline: 1.7898x; 1.7898x over previous
//
#include <hip/hip_runtime.h>
#include <stdint.h>

typedef __attribute__((ext_vector_type(8))) short short8;
typedef __attribute__((ext_vector_type(4))) float fl4;
typedef __attribute__((ext_vector_type(2))) float fl2;
typedef __attribute__((ext_vector_type(8))) unsigned short us8;

#define SAT_HI 1.0e6f
#define ZSLOT 262144u            // elements per z slot (64*4096 bf16)

__device__ __forceinline__ unsigned short f2bf(float f) {
  unsigned u = __float_as_uint(f);
  u += 0x7fffu + ((u >> 16) & 1u);   // RNE
  return (unsigned short)(u >> 16);
}
__device__ __forceinline__ float clipf(float x) {
  return fminf(fmaxf(x, 0.0f), SAT_HI);
}

__device__ __forceinline__ void gload16(const void* g, void* l) {
  __builtin_amdgcn_global_load_lds(
      (const __attribute__((address_space(1))) void*)g,
      (__attribute__((address_space(3))) void*)l, 16, 0, 0);
}

// ---- pack W (f32 [N][N]) into bf16 MFMA B-fragments ----
// u = [ct:7][w:3][cf:1][ki:4][lane:6]; col-tile ct owns n in [32ct,32ct+32),
// wave w owns k in [512w,512w+512). lane: n = 32ct+16cf+(lane&15),
// k = 512w+32ki+8*(lane>>4). B[k][n] = W[n][k]  (y = z @ W^T)
__global__ __launch_bounds__(256) void prep_kernel(const float* __restrict__ W,
                                                   unsigned short* __restrict__ wfrag) {
  unsigned u = blockIdx.x * 256u + threadIdx.x;        // < 2097152
  unsigned lane = u & 63u, lo = lane & 15u, hi = lane >> 4;
  unsigned ki = (u >> 6) & 15u;
  unsigned cf = (u >> 10) & 1u;
  unsigned w = (u >> 11) & 7u;
  unsigned ct = u >> 14;               // 0..127
  unsigned n = ct * 32u + cf * 16u + lo;
  unsigned k = w * 512u + ki * 32u + hi * 8u;
  const float* src = W + (size_t)n * 4096u + k;
  fl4 s0 = *(const fl4*)(src);
  fl4 s1 = *(const fl4*)(src + 4);
  us8 o;
  o[0] = f2bf(s0[0]); o[1] = f2bf(s0[1]); o[2] = f2bf(s0[2]); o[3] = f2bf(s0[3]);
  o[4] = f2bf(s1[0]); o[5] = f2bf(s1[1]); o[6] = f2bf(s1[2]); o[7] = f2bf(s1[3]);
  *(us8*)(wfrag + (size_t)u * 8u) = o;
}

__global__ __launch_bounds__(512, 2) void persist_kernel(
    const float* __restrict__ xin,     // [C][B][T]
    const float* __restrict__ state0,  // [B][N]
    const float* __restrict__ mask,    // [N]
    const float* __restrict__ enc,     // [C][N]
    const float* __restrict__ bias,    // [N]
    const float* __restrict__ decw,    // [C][N]
    const unsigned short* __restrict__ wfrag,
    unsigned short* __restrict__ zbuf, // [3][B][N] bf16
    float* __restrict__ dsc8,          // [8][C][B][T] f32, atomically accumulated
    int* __restrict__ cnt) {
  // 8 waves x 16 KB stage buffers = 128 KB; after MFMA each wave's f32 partial
  // block [32][36] (4608 B) is aliased into its OWN stage buffer.
  __shared__ __align__(16) unsigned char sm[131072];

  const int tid = threadIdx.x;
  const int wave = tid >> 6;           // 0..7, owns K-eighth
  const int lane = tid & 63;
  const int lo = lane & 15, hi = lane >> 4;
  const int g = blockIdx.x;
  const int rt = g & 1;                // row-half: rows [32rt, 32rt+32)
  const int ct = g >> 1;               // col-tile 0..127: cols [32ct, 32ct+32)
  const int xcd = g & 7;               // same-XCD blocks share rt (xcd&1==rt)
  float* dscg = dsc8 + (size_t)(ct & 7) * 131072u;   // decode copy, 16-way fan-in
  int* hcnt = cnt + rt * 32;           // per-half barrier counter
  int* xcnt = cnt + 64 + xcd * 32;     // per-XCD arrival line

  // persistent W fragments: 32 x short8 = 128 VGPRs  (wf[cf*16+ki])
  short8 wf[32];
  {
    const short8* wp = (const short8*)wfrag + (size_t)(ct * 8 + wave) * 32u * 64u + lane;
#pragma unroll
    for (int f = 0; f < 32; ++f) wf[f] = wp[(size_t)f * 64u];
  }

  // phase-B role: 2 outputs/thread: local row r = tid>>4, cols c2,c2+1
  const int r = tid >> 4, c2 = (tid & 15) * 2;
  const int b = rt * 32 + r;           // global batch row
  const int n0 = ct * 32 + c2;         // global neuron col (even)
  const fl2 mk = *(const fl2*)(mask + n0);
  const fl2 bi = *(const fl2*)(bias + n0);
  const fl2 e0 = *(const fl2*)(enc + n0);
  const fl2 e1 = *(const fl2*)(enc + 4096 + n0);
  const fl2 e2 = *(const fl2*)(enc + 8192 + n0);
  const fl2 e3 = *(const fl2*)(enc + 12288 + n0);
  const fl2 w0 = *(const fl2*)(decw + n0);
  const fl2 w1 = *(const fl2*)(decw + 4096 + n0);
  const fl2 w2 = *(const fl2*)(decw + 8192 + n0);
  const fl2 w3 = *(const fl2*)(decw + 12288 + n0);
  const float* xp = xin + b * 512;     // x[ch][b][t] = xp[ch*32768 + t]
  const int kwb = wave * 1024;         // byte offset of wave's K-slice in a z row
  const int rbase = rt * 32;

  char* mybuf = (char*)sm + wave * 16384;
  float* pown = (float*)mybuf;         // aliased partial region [32][36] f32

  int ep = 0;

  // prologue: z_0 -> slot 0 (write-through)
  {
    fl2 st = *(const fl2*)(state0 + (size_t)b * 4096u + n0);
    float x0 = xp[0], x1 = xp[32768], x2 = xp[65536], x3 = xp[98304];
    float z0 = st[0] + mk[0] * (x0 * e0[0] + x1 * e1[0] + x2 * e2[0] + x3 * e3[0]);
    float z1 = st[1] + mk[1] * (x0 * e0[1] + x1 * e1[1] + x2 * e2[1] + x3 * e3[1]);
    unsigned pack = (unsigned)f2bf(z0) | ((unsigned)f2bf(z1) << 16);
    __hip_atomic_store((unsigned*)(zbuf + (size_t)b * 4096u + n0), pack,
                       __ATOMIC_RELAXED, __HIP_MEMORY_SCOPE_SYSTEM);
  }
  {
    ++ep;
    __syncthreads();
    if (tid == 0) {
      int old = __hip_atomic_fetch_add(xcnt, 1, __ATOMIC_RELAXED, __HIP_MEMORY_SCOPE_AGENT);
      if (old == ep * 32 - 1)
        __hip_atomic_fetch_add(hcnt, 1, __ATOMIC_RELAXED, __HIP_MEMORY_SCOPE_AGENT);
      while (__hip_atomic_load(hcnt, __ATOMIC_RELAXED, __HIP_MEMORY_SCOPE_AGENT) < ep * 4)
        __builtin_amdgcn_s_sleep(1);
      (void)__hip_atomic_load(hcnt, __ATOMIC_ACQUIRE, __HIP_MEMORY_SCOPE_AGENT);
    }
    __syncthreads();
  }

  float pd0 = 0.f, pd1 = 0.f, pd2 = 0.f, pd3 = 0.f;  // deferred decode (t-1)
  int slot = 0;
  for (int t = 0; t < 512; ++t) {
    const char* zsrc = (const char*)(zbuf + (size_t)slot * ZSLOT) + kwb;

    // ---- sub-phase 0: stage rows rbase..rbase+16 (wave's K-slice) ----
#pragma unroll
    for (int j = 0; j < 16; ++j)
      gload16(zsrc + (size_t)(rbase + j) * 8192 + (((unsigned)lane ^ (unsigned)(j & 7)) << 4),
              mybuf + j * 1024);
    // deferred decode atomics (drain under staging)
    if (t > 0 && (tid & 15) == 0) {
      atomicAdd(dscg + b * 512 + (t - 1), pd0);
      atomicAdd(dscg + 32768 + b * 512 + (t - 1), pd1);
      atomicAdd(dscg + 65536 + b * 512 + (t - 1), pd2);
      atomicAdd(dscg + 98304 + b * 512 + (t - 1), pd3);
    }
    // next-step x prefetch
    float xv0 = 0.f, xv1 = 0.f, xv2 = 0.f, xv3 = 0.f;
    if (t < 511) {
      xv0 = xp[t + 1]; xv1 = xp[32768 + t + 1];
      xv2 = xp[65536 + t + 1]; xv3 = xp[98304 + t + 1];
    }
    asm volatile("s_waitcnt vmcnt(0)" ::: "memory");
    __builtin_amdgcn_sched_barrier(0);
    fl4 a00 = {0.f,0.f,0.f,0.f}, a01 = a00;
#pragma unroll
    for (int ki = 0; ki < 16; ++ki) {
      short8 a = *(const short8*)(mybuf + lo * 1024 +
                                  ((((unsigned)(ki * 4 + hi)) ^ (unsigned)(lo & 7)) << 4));
      a00 = __builtin_amdgcn_mfma_f32_16x16x32_bf16(a, wf[ki], a00, 0, 0, 0);
      a01 = __builtin_amdgcn_mfma_f32_16x16x32_bf16(a, wf[16 + ki], a01, 0, 0, 0);
    }
    // own-wave ds reads must finish before restaging same buffer
    asm volatile("s_waitcnt lgkmcnt(0)" ::: "memory");
    __builtin_amdgcn_sched_barrier(0);

    // ---- sub-phase 1: stage rows rbase+16..rbase+32 ----
#pragma unroll
    for (int j = 0; j < 16; ++j)
      gload16(zsrc + (size_t)(rbase + 16 + j) * 8192 + (((unsigned)lane ^ (unsigned)(j & 7)) << 4),
              mybuf + j * 1024);
    asm volatile("s_waitcnt vmcnt(0)" ::: "memory");
    __builtin_amdgcn_sched_barrier(0);
    fl4 a10 = {0.f,0.f,0.f,0.f}, a11 = a10;
#pragma unroll
    for (int ki = 0; ki < 16; ++ki) {
      short8 a = *(const short8*)(mybuf + lo * 1024 +
                                  ((((unsigned)(ki * 4 + hi)) ^ (unsigned)(lo & 7)) << 4));
      a10 = __builtin_amdgcn_mfma_f32_16x16x32_bf16(a, wf[ki], a10, 0, 0, 0);
      a11 = __builtin_amdgcn_mfma_f32_16x16x32_bf16(a, wf[16 + ki], a11, 0, 0, 0);
    }
    // ---- stash per-wave partials [32][36] (aliased into own buffer) ----
#pragma unroll
    for (int rr = 0; rr < 4; ++rr) {
      pown[(hi * 4 + rr) * 36 + lo] = a00[rr];
      pown[(hi * 4 + rr) * 36 + 16 + lo] = a01[rr];
      pown[(16 + hi * 4 + rr) * 36 + lo] = a10[rr];
      pown[(16 + hi * 4 + rr) * 36 + 16 + lo] = a11[rr];
    }
    __syncthreads();

    // ---- phase B: reduce over 8 waves + state update ----
    float y0 = 0.f, y1 = 0.f;
#pragma unroll
    for (int w = 0; w < 8; ++w) {
      fl2 v = *(const fl2*)((const char*)sm + w * 16384 + (size_t)(r * 36 + c2) * 4u);
      y0 += v[0]; y1 += v[1];
    }
    float sn0 = mk[0] * (bi[0] + clipf(y0));
    float sn1 = mk[1] * (bi[1] + clipf(y1));

    // next z FIRST (critical path for step t+1), write-through
    if (t < 511) {
      int ns = slot + 1; if (ns == 3) ns = 0;
      float z0 = sn0 + mk[0] * (xv0 * e0[0] + xv1 * e1[0] + xv2 * e2[0] + xv3 * e3[0]);
      float z1 = sn1 + mk[1] * (xv0 * e0[1] + xv1 * e1[1] + xv2 * e2[1] + xv3 * e3[1]);
      unsigned pack = (unsigned)f2bf(z0) | ((unsigned)f2bf(z1) << 16);
      __hip_atomic_store((unsigned*)(zbuf + (size_t)ns * ZSLOT + (size_t)b * 4096u + n0),
                         pack, __ATOMIC_RELAXED, __HIP_MEMORY_SCOPE_SYSTEM);
      slot = ns;
    }

    // ---- barrier ARRIVE (z stores drained by syncthreads' vmcnt drain) ----
    int e = 0;
    if (t < 511) {
      e = ++ep;
      __syncthreads();
      if (tid == 0) {
        int old = __hip_atomic_fetch_add(xcnt, 1, __ATOMIC_RELAXED, __HIP_MEMORY_SCOPE_AGENT);
        if (old == e * 32 - 1)
          __hip_atomic_fetch_add(hcnt, 1, __ATOMIC_RELAXED, __HIP_MEMORY_SCOPE_AGENT);
      }
    }

    // ---- decode reduce over this block's 32 cols (overlaps arrivals) ----
    float d0 = sn0 * w0[0] + sn1 * w0[1];
    float d1 = sn0 * w1[0] + sn1 * w1[1];
    float d2 = sn0 * w2[0] + sn1 * w2[1];
    float d3 = sn0 * w3[0] + sn1 * w3[1];
    d0 += __shfl_xor(d0, 1); d0 += __shfl_xor(d0, 2); d0 += __shfl_xor(d0, 4); d0 += __shfl_xor(d0, 8);
    d1 += __shfl_xor(d1, 1); d1 += __shfl_xor(d1, 2); d1 += __shfl_xor(d1, 4); d1 += __shfl_xor(d1, 8);
    d2 += __shfl_xor(d2, 1); d2 += __shfl_xor(d2, 2); d2 += __shfl_xor(d2, 4); d2 += __shfl_xor(d2, 8);
    d3 += __shfl_xor(d3, 1); d3 += __shfl_xor(d3, 2); d3 += __shfl_xor(d3, 4); d3 += __shfl_xor(d3, 8);
    pd0 = d0; pd1 = d1; pd2 = d2; pd3 = d3;

    // ---- barrier WAIT ----
    if (t < 511) {
      if (tid == 0) {
        while (__hip_atomic_load(hcnt, __ATOMIC_RELAXED, __HIP_MEMORY_SCOPE_AGENT) < e * 4)
          __builtin_amdgcn_s_sleep(1);
        (void)__hip_atomic_load(hcnt, __ATOMIC_ACQUIRE, __HIP_MEMORY_SCOPE_AGENT);
      }
      __syncthreads();
    }
  }
  // flush last step's decode
  if ((tid & 15) == 0) {
    atomicAdd(dscg + b * 512 + 511, pd0);
    atomicAdd(dscg + 32768 + b * 512 + 511, pd1);
    atomicAdd(dscg + 65536 + b * 512 + 511, pd2);
    atomicAdd(dscg + 98304 + b * 512 + 511, pd3);
  }
}

__global__ __launch_bounds__(256) void final_kernel(const float* __restrict__ dsc8,
                                                    const float* __restrict__ decb,
                                                    float* __restrict__ out) {
  const unsigned u = blockIdx.x * 256u + threadIdx.x;  // < 131072, [C][B][T]
  const unsigned c = u >> 15;
  float s = decb[c];
#pragma unroll
  for (int g = 0; g < 8; ++g) s += dsc8[(size_t)g * 131072u + u];
  out[u] = clipf(s);
}

extern "C" void kernel_launch(void* const* d_in, const int* in_sizes, int n_in,
                              void* d_out, int out_size, void* d_ws, size_t ws_size,
                              hipStream_t stream) {
  const float* xin  = (const float*)d_in[0];
  const float* st   = (const float*)d_in[1];
  const float* mask = (const float*)d_in[2];
  const float* W    = (const float*)d_in[3];
  const float* enc  = (const float*)d_in[4];
  const float* bias = (const float*)d_in[5];
  const float* decw = (const float*)d_in[6];
  const float* decb = (const float*)d_in[7];
  char* ws = (char*)d_ws;

  const size_t WFRAG_B = 33554432ull;             // 32 MB
  const size_t Z_B     = 3ull * 524288ull;        // 1.5 MB (3-slot ring)
  const size_t DSC_B   = 4194304ull;              // 8 copies x 512 KB
  unsigned short* wfrag = (unsigned short*)(ws);
  unsigned short* zbuf  = (unsigned short*)(ws + WFRAG_B);
  float* dsc8 = (float*)(ws + WFRAG_B + Z_B);
  int* cnt    = (int*)(ws + WFRAG_B + Z_B + DSC_B);

  hipMemsetAsync(cnt, 0, 4096, stream);
  hipMemsetAsync(dsc8, 0, DSC_B, stream);
  prep_kernel<<<8192, 256, 0, stream>>>(W, wfrag);
  persist_kernel<<<256, 512, 0, stream>>>(xin, st, mask, enc, bias, decw,
                                          wfrag, zbuf, dsc8, cnt);
  final_kernel<<<512, 256, 0, stream>>>(dsc8, decb, (float*)d_out);
}

// Round 9
// 4683.570 us; speedup vs baseline: 2.1413x; 1.1964x over previous
//
#include <hip/hip_runtime.h>
#include <stdint.h>

typedef __attribute__((ext_vector_type(8))) short short8;
typedef __attribute__((ext_vector_type(4))) float fl4;
typedef __attribute__((ext_vector_type(2))) float fl2;
typedef __attribute__((ext_vector_type(8))) unsigned short us8;

#define SAT_HI 1.0e6f
#define ZSLOT 262144u            // elements per z slot (64*4096 bf16)

__device__ __forceinline__ unsigned short f2bf(float f) {
  unsigned u = __float_as_uint(f);
  u += 0x7fffu + ((u >> 16) & 1u);   // RNE
  return (unsigned short)(u >> 16);
}
__device__ __forceinline__ float clipf(float x) {
  return fminf(fmaxf(x, 0.0f), SAT_HI);
}

__device__ __forceinline__ void gload16(const void* g, void* l) {
  __builtin_amdgcn_global_load_lds(
      (const __attribute__((address_space(1))) void*)g,
      (__attribute__((address_space(3))) void*)l, 16, 0, 0);
}

// stage one 8 KB chunk: 16 rows x 512 B (K-half h) via 8 row-pair gload16.
// LDS layout [16 rows][512 B], 16B-granule XOR-swizzled by row&7 (source-side).
__device__ __forceinline__ void stage_chunk(const char* zsrc, char* dst,
                                            int rows0, int h, int lane) {
#pragma unroll
  for (int i = 0; i < 8; ++i) {
    const int rl = 2 * i + (lane >> 5);                       // row in chunk
    const unsigned q = (unsigned)(lane & 31) ^ ((unsigned)rl & 7u);
    gload16(zsrc + (size_t)(rows0 + rl) * 8192 + h * 512 + (q << 4),
            dst + i * 1024);
  }
}

// per-wave wait on a producer-group counter (LLC-scope relaxed poll)
__device__ __forceinline__ void gwait(const int* pgc, int target) {
  while (__hip_atomic_load(pgc, __ATOMIC_RELAXED, __HIP_MEMORY_SCOPE_AGENT) < target)
    __builtin_amdgcn_s_sleep(1);
  __builtin_amdgcn_sched_barrier(0);
}

#define MFMA_CHUNK(BUF, H, ACCA, ACCB)                                         \
  _Pragma("unroll")                                                            \
  for (int ki_ = 0; ki_ < 8; ++ki_) {                                          \
    short8 a_ = *(const short8*)((BUF) + lo * 512 +                            \
        ((((unsigned)(ki_ * 4 + hi)) ^ ((unsigned)lo & 7u)) << 4));            \
    ACCA = __builtin_amdgcn_mfma_f32_16x16x32_bf16(a_, wf[(H) * 8 + ki_], ACCA, 0, 0, 0); \
    ACCB = __builtin_amdgcn_mfma_f32_16x16x32_bf16(a_, wf[16 + (H) * 8 + ki_], ACCB, 0, 0, 0); \
  }

// ---- pack W (f32 [N][N]) into bf16 MFMA B-fragments ----
// u = [ct:7][w:3][cf:1][ki:4][lane:6]; col-tile ct owns n in [32ct,32ct+32),
// wave w owns k in [512w,512w+512). lane: n = 32ct+16cf+(lane&15),
// k = 512w+32ki+8*(lane>>4). B[k][n] = W[n][k]  (y = z @ W^T)
__global__ __launch_bounds__(256) void prep_kernel(const float* __restrict__ W,
                                                   unsigned short* __restrict__ wfrag) {
  unsigned u = blockIdx.x * 256u + threadIdx.x;        // < 2097152
  unsigned lane = u & 63u, lo = lane & 15u, hi = lane >> 4;
  unsigned ki = (u >> 6) & 15u;
  unsigned cf = (u >> 10) & 1u;
  unsigned w = (u >> 11) & 7u;
  unsigned ct = u >> 14;               // 0..127
  unsigned n = ct * 32u + cf * 16u + lo;
  unsigned k = w * 512u + ki * 32u + hi * 8u;
  const float* src = W + (size_t)n * 4096u + k;
  fl4 s0 = *(const fl4*)(src);
  fl4 s1 = *(const fl4*)(src + 4);
  us8 o;
  o[0] = f2bf(s0[0]); o[1] = f2bf(s0[1]); o[2] = f2bf(s0[2]); o[3] = f2bf(s0[3]);
  o[4] = f2bf(s1[0]); o[5] = f2bf(s1[1]); o[6] = f2bf(s1[2]); o[7] = f2bf(s1[3]);
  *(us8*)(wfrag + (size_t)u * 8u) = o;
}

__global__ __launch_bounds__(512, 2) void persist_kernel(
    const float* __restrict__ xin,     // [C][B][T]
    const float* __restrict__ state0,  // [B][N]
    const float* __restrict__ mask,    // [N]
    const float* __restrict__ enc,     // [C][N]
    const float* __restrict__ bias,    // [N]
    const float* __restrict__ decw,    // [C][N]
    const unsigned short* __restrict__ wfrag,
    unsigned short* __restrict__ zbuf, // [R][B][N] bf16 monotone ring
    float* __restrict__ dsc8,          // [8][C][B][T] f32, atomically accumulated
    int* __restrict__ cnt,             // [2][8] producer-group counters (32-int lines)
    int R, int invP) {
  // 8 waves x (2 x 8 KB ping-pong stage buffers) = 128 KB; wave's f32 partial
  // block [32][36] (4608 B) aliases the head of its buf0 after consumption.
  __shared__ __align__(16) unsigned char sm[131072];

  const int tid = threadIdx.x;
  const int wave = tid >> 6;           // 0..7, owns K-eighth
  const int lane = tid & 63;
  const int lo = lane & 15, hi = lane >> 4;
  const int g = blockIdx.x;
  const int rt = g & 1;                // row-half: rows [32rt, 32rt+32)
  const int ct = g >> 1;               // col-tile 0..127: cols [32ct, 32ct+32)
  float* dscg = dsc8 + (size_t)(ct & 7) * 131072u;
  int* mypgc = cnt + (rt * 8 + (ct >> 4)) * 32;  // this block posts here
  int* wpgc  = cnt + (rt * 8 + wave) * 32;       // this wave waits here

  // persistent W fragments: 32 x short8 = 128 regs (wf[cf*16+ki])
  short8 wf[32];
  {
    const short8* wp = (const short8*)wfrag + (size_t)(ct * 8 + wave) * 32u * 64u + lane;
#pragma unroll
    for (int f = 0; f < 32; ++f) wf[f] = wp[(size_t)f * 64u];
  }

  // phase-B role: 2 outputs/thread: local row r = tid>>4, cols c2,c2+1
  const int r = tid >> 4, c2 = (tid & 15) * 2;
  const int b = rt * 32 + r;
  const int n0 = ct * 32 + c2;
  const fl2 mk = *(const fl2*)(mask + n0);
  const fl2 bi = *(const fl2*)(bias + n0);
  const fl2 e0 = *(const fl2*)(enc + n0);
  const fl2 e1 = *(const fl2*)(enc + 4096 + n0);
  const fl2 e2 = *(const fl2*)(enc + 8192 + n0);
  const fl2 e3 = *(const fl2*)(enc + 12288 + n0);
  const fl2 w0 = *(const fl2*)(decw + n0);
  const fl2 w1 = *(const fl2*)(decw + 4096 + n0);
  const fl2 w2 = *(const fl2*)(decw + 8192 + n0);
  const fl2 w3 = *(const fl2*)(decw + 12288 + n0);
  const float* xp = xin + b * 512;
  const size_t kwb = (size_t)wave * 1024u;   // wave's K-slice byte offset in a z row
  const int rbase = rt * 32;

  char* buf0 = (char*)sm + wave * 16384;
  char* buf1 = buf0 + 8192;
  float* pown = (float*)buf0;          // aliased partial region [32][36] f32

  // prologue: z_0 -> slot 0 (write-through), then post
  {
    fl2 st = *(const fl2*)(state0 + (size_t)b * 4096u + n0);
    float x0 = xp[0], x1 = xp[32768], x2 = xp[65536], x3 = xp[98304];
    float z0 = st[0] + mk[0] * (x0 * e0[0] + x1 * e1[0] + x2 * e2[0] + x3 * e3[0]);
    float z1 = st[1] + mk[1] * (x0 * e0[1] + x1 * e1[1] + x2 * e2[1] + x3 * e3[1]);
    unsigned pack = (unsigned)f2bf(z0) | ((unsigned)f2bf(z1) << 16);
    __hip_atomic_store((unsigned*)(zbuf + (size_t)b * 4096u + n0), pack,
                       __ATOMIC_RELAXED, __HIP_MEMORY_SCOPE_SYSTEM);
  }
  __syncthreads();                     // drains all waves' z stores
  if (tid == 0)
    __hip_atomic_fetch_add(mypgc, 1, __ATOMIC_RELAXED, __HIP_MEMORY_SCOPE_AGENT);

  float pd0 = 0.f, pd1 = 0.f, pd2 = 0.f, pd3 = 0.f;  // deferred decode (t-1)
  int cur = 0;
  int invc = invP;
  for (int t = 0; t < 512; ++t) {
    // next-step x prefetch (retires during wait/staging)
    float xv0 = 0.f, xv1 = 0.f, xv2 = 0.f, xv3 = 0.f;
    if (t < 511) {
      xv0 = xp[t + 1]; xv1 = xp[32768 + t + 1];
      xv2 = xp[65536 + t + 1]; xv3 = xp[98304 + t + 1];
    }

    // ---- wave-level wait: only THIS wave's 16 producers ----
    gwait(wpgc, 16 * (t + 1));
    const char* zsrc = (const char*)(zbuf + (size_t)cur * ZSLOT) + kwb;

    // ---- pipelined staging (counted vmcnt, ping-pong 2x8KB) + MFMA ----
    fl4 a00 = {0.f,0.f,0.f,0.f}, a01 = a00, a10 = a00, a11 = a00;
    stage_chunk(zsrc, buf0, rbase, 0, lane);        // C0 (h0, rows 0-15)
    stage_chunk(zsrc, buf1, rbase + 16, 0, lane);   // C1 (h0, rows 16-31)
    asm volatile("s_waitcnt vmcnt(8)" ::: "memory");   // C0 ready
    __builtin_amdgcn_sched_barrier(0);
    MFMA_CHUNK(buf0, 0, a00, a01);
    asm volatile("s_waitcnt lgkmcnt(0)" ::: "memory");
    __builtin_amdgcn_sched_barrier(0);
    stage_chunk(zsrc, buf0, rbase, 1, lane);        // C2 (h1, rows 0-15)
    asm volatile("s_waitcnt vmcnt(8)" ::: "memory");   // C1 ready
    __builtin_amdgcn_sched_barrier(0);
    MFMA_CHUNK(buf1, 0, a10, a11);
    asm volatile("s_waitcnt lgkmcnt(0)" ::: "memory");
    __builtin_amdgcn_sched_barrier(0);
    stage_chunk(zsrc, buf1, rbase + 16, 1, lane);   // C3 (h1, rows 16-31)
    asm volatile("s_waitcnt vmcnt(8)" ::: "memory");   // C2 ready
    __builtin_amdgcn_sched_barrier(0);
    MFMA_CHUNK(buf0, 1, a00, a01);
    // prev-step decode atomics, issued UNCONDITIONALLY (exactly 4 per wave)
    // so the following vmcnt(4) always retires all 8 C3 loads. At t==0 the
    // pd values are 0.0f and the clamped index makes atomicAdd(x, 0) a no-op.
    if ((tid & 15) == 0) {
      const int ti = (t > 0) ? (t - 1) : 0;
      atomicAdd(dscg + b * 512 + ti, pd0);
      atomicAdd(dscg + 32768 + b * 512 + ti, pd1);
      atomicAdd(dscg + 65536 + b * 512 + ti, pd2);
      atomicAdd(dscg + 98304 + b * 512 + ti, pd3);
    }
    asm volatile("s_waitcnt vmcnt(4)" ::: "memory");   // C3 ready (atomics in flight)
    __builtin_amdgcn_sched_barrier(0);
    MFMA_CHUNK(buf1, 1, a10, a11);
    asm volatile("s_waitcnt lgkmcnt(0)" ::: "memory");
    __builtin_amdgcn_sched_barrier(0);

    // ---- stash per-wave partials [32][36] into own buf0 head ----
#pragma unroll
    for (int rr = 0; rr < 4; ++rr) {
      pown[(hi * 4 + rr) * 36 + lo] = a00[rr];
      pown[(hi * 4 + rr) * 36 + 16 + lo] = a01[rr];
      pown[(16 + hi * 4 + rr) * 36 + lo] = a10[rr];
      pown[(16 + hi * 4 + rr) * 36 + 16 + lo] = a11[rr];
    }
    __syncthreads();

    // ---- phase B: reduce over 8 waves + state update ----
    float y0 = 0.f, y1 = 0.f;
#pragma unroll
    for (int w = 0; w < 8; ++w) {
      fl2 v = *(const fl2*)((const char*)sm + w * 16384 + (size_t)(r * 36 + c2) * 4u);
      y0 += v[0]; y1 += v[1];
    }
    float sn0 = mk[0] * (bi[0] + clipf(y0));
    float sn1 = mk[1] * (bi[1] + clipf(y1));

    // next z (critical path), write-through to next ring slot
    if (t < 511) {
      int ns = cur + 1; if (ns == R) ns = 0;
      float z0 = sn0 + mk[0] * (xv0 * e0[0] + xv1 * e1[0] + xv2 * e2[0] + xv3 * e3[0]);
      float z1 = sn1 + mk[1] * (xv0 * e0[1] + xv1 * e1[1] + xv2 * e2[1] + xv3 * e3[1]);
      unsigned pack = (unsigned)f2bf(z0) | ((unsigned)f2bf(z1) << 16);
      __hip_atomic_store((unsigned*)(zbuf + (size_t)ns * ZSLOT + (size_t)b * 4096u + n0),
                         pack, __ATOMIC_RELAXED, __HIP_MEMORY_SCOPE_SYSTEM);
      cur = ns;
    }
    __syncthreads();                   // drains ALL waves' z stores (+ pown reads done)

    if (t < 511 && tid == 0) {
      __hip_atomic_fetch_add(mypgc, 1, __ATOMIC_RELAXED, __HIP_MEMORY_SCOPE_AGENT);
      // periodic L2 invalidation only if ring reuses addresses (R < 513)
      if (--invc == 0) {
        invc = invP;
        (void)__hip_atomic_load(mypgc, __ATOMIC_ACQUIRE, __HIP_MEMORY_SCOPE_AGENT);
      }
    }

    // ---- decode reduce (overlaps other blocks' posting) ----
    float d0 = sn0 * w0[0] + sn1 * w0[1];
    float d1 = sn0 * w1[0] + sn1 * w1[1];
    float d2 = sn0 * w2[0] + sn1 * w2[1];
    float d3 = sn0 * w3[0] + sn1 * w3[1];
    d0 += __shfl_xor(d0, 1); d0 += __shfl_xor(d0, 2); d0 += __shfl_xor(d0, 4); d0 += __shfl_xor(d0, 8);
    d1 += __shfl_xor(d1, 1); d1 += __shfl_xor(d1, 2); d1 += __shfl_xor(d1, 4); d1 += __shfl_xor(d1, 8);
    d2 += __shfl_xor(d2, 1); d2 += __shfl_xor(d2, 2); d2 += __shfl_xor(d2, 4); d2 += __shfl_xor(d2, 8);
    d3 += __shfl_xor(d3, 1); d3 += __shfl_xor(d3, 2); d3 += __shfl_xor(d3, 4); d3 += __shfl_xor(d3, 8);
    pd0 = d0; pd1 = d1; pd2 = d2; pd3 = d3;
  }
  // flush last step's decode
  if ((tid & 15) == 0) {
    atomicAdd(dscg + b * 512 + 511, pd0);
    atomicAdd(dscg + 32768 + b * 512 + 511, pd1);
    atomicAdd(dscg + 65536 + b * 512 + 511, pd2);
    atomicAdd(dscg + 98304 + b * 512 + 511, pd3);
  }
}

__global__ __launch_bounds__(256) void final_kernel(const float* __restrict__ dsc8,
                                                    const float* __restrict__ decb,
                                                    float* __restrict__ out) {
  const unsigned u = blockIdx.x * 256u + threadIdx.x;  // < 131072, [C][B][T]
  const unsigned c = u >> 15;
  float s = decb[c];
#pragma unroll
  for (int g = 0; g < 8; ++g) s += dsc8[(size_t)g * 131072u + u];
  out[u] = clipf(s);
}

extern "C" void kernel_launch(void* const* d_in, const int* in_sizes, int n_in,
                              void* d_out, int out_size, void* d_ws, size_t ws_size,
                              hipStream_t stream) {
  const float* xin  = (const float*)d_in[0];
  const float* st   = (const float*)d_in[1];
  const float* mask = (const float*)d_in[2];
  const float* W    = (const float*)d_in[3];
  const float* enc  = (const float*)d_in[4];
  const float* bias = (const float*)d_in[5];
  const float* decw = (const float*)d_in[6];
  const float* decb = (const float*)d_in[7];
  char* ws = (char*)d_ws;

  const size_t WFRAG_B = 33554432ull;             // 32 MB
  const size_t SLOT_B  = 524288ull;               // 512 KB per z slot
  const size_t DSC_B   = 4194304ull;              // 8 copies x 512 KB
  const size_t CNT_B   = 4096ull;
  const size_t fixed   = WFRAG_B + DSC_B + CNT_B;

  int R = 4;
  if (ws_size > fixed) {
    size_t r = (ws_size - fixed) / SLOT_B;
    R = (r > 513) ? 513 : (int)r;
    if (R < 4) R = 4;
  }
  const int invP = (R >= 513) ? (1 << 30) : (R - 3);

  unsigned short* wfrag = (unsigned short*)(ws);
  unsigned short* zbuf  = (unsigned short*)(ws + WFRAG_B);
  float* dsc8 = (float*)(ws + WFRAG_B + (size_t)R * SLOT_B);
  int* cnt    = (int*)(ws + WFRAG_B + (size_t)R * SLOT_B + DSC_B);

  hipMemsetAsync(cnt, 0, CNT_B, stream);
  hipMemsetAsync(dsc8, 0, DSC_B, stream);
  prep_kernel<<<8192, 256, 0, stream>>>(W, wfrag);
  persist_kernel<<<256, 512, 0, stream>>>(xin, st, mask, enc, bias, decw,
                                          wfrag, zbuf, dsc8, cnt, R, invP);
  final_kernel<<<512, 256, 0, stream>>>(dsc8, decb, (float*)d_out);
}